// Round 3
// baseline (40132.993 us; speedup 1.0000x reference)
//
#include <hip/hip_runtime.h>

// Problem dims (fixed by reference)
#define T_SEQ 512
#define B_SZ  64
#define IN_SZ 512
#define H_SZ  1024
#define NBLK  256   // 128 blocks layer0 + 128 blocks layer1, 1 block/CU (LDS-forced)
#define NTHR  512   // 8 waves
#define RING  8     // h1 ring depth (layer-0 max lead over layer-1)

typedef _Float16 f16;
typedef _Float16 half8 __attribute__((ext_vector_type(8)));
typedef float    f32x4 __attribute__((ext_vector_type(4)));

// LDS layout (dynamic): wfrag [0,128K) | partial tiles [128K,+16K) | c [+2K) | bias [+128B)
#define SM_WFRAG 0
#define SM_PART  131072
#define SM_C     (131072 + 16384)
#define SM_BIAS  (131072 + 16384 + 2048)
#define SMEM_BYTES (131072 + 16384 + 2048 + 128)

struct Params {
    const float *x;
    const float *wih0, *whh0, *bih0, *bhh0;
    const float *wih1, *whh1, *bih1, *bhh1;
    f16 *h1ring;   // [RING][B][H]
    f16 *h2all;    // [T][B][H]
    int *cnt0, *cnt1;
};

__device__ __forceinline__ float sigf(float x)     { return 1.f / (1.f + __expf(-x)); }
__device__ __forceinline__ float tanhfast(float x) { return 2.f / (1.f + __expf(-2.f * x)) - 1.f; }

// ---------------------------------------------------------------------------
// Persistent 2-layer LSTM. blocks 0..127: layer 0 (steps s=0..511, free-runs
// ahead, bounded by RING). blocks 128..255: layer 1 (steps t=0..511).
// Each block owns 8 h-columns (N=32 gate rows = i,f,g,o x 8), weights live in
// LDS in MFMA-B fragment order. Sync: per-layer release/acquire counters.
// ---------------------------------------------------------------------------
__global__ __launch_bounds__(NTHR, 2) void persist_kernel(Params p)
{
    extern __shared__ char smem[];
    f16*   wfrag = (f16*)(smem + SM_WFRAG);
    float* P     = (float*)(smem + SM_PART);   // 16 slots x 256 f32 (tiles transposed [col][row])
    float* c_lds = (float*)(smem + SM_C);      // [64][8] cell state, persistent
    float* bl    = (float*)(smem + SM_BIAS);   // [4 gates][8 cols]

    const int tid = threadIdx.x;
    const int l   = tid & 63, wv = tid >> 6;
    const int n16 = l & 15,  q  = l >> 4;
    const int layer = blockIdx.x >> 7;
    const int jb    = (blockIdx.x & 127) * 8;

    // ---- one-time staging: weights fp32 -> f16 fragments in LDS ----
    {
        const int gate0 = n16 >> 3, c8 = n16 & 7;
        const int nfrag = layer ? 128 : 96;   // (K/32)*2 nt
        for (int f = wv; f < nfrag; f += 8) {
            int kstep = f >> 1, nt = f & 1;
            int wrow = (nt * 2 + gate0) * H_SZ + jb + c8;
            const float* src;
            if (layer == 0) {
                src = (kstep < 16) ? p.wih0 + (size_t)wrow * IN_SZ + kstep * 32 + q * 8
                                   : p.whh0 + (size_t)wrow * H_SZ + (kstep - 16) * 32 + q * 8;
            } else {
                src = (kstep < 32) ? p.wih1 + (size_t)wrow * H_SZ + kstep * 32 + q * 8
                                   : p.whh1 + (size_t)wrow * H_SZ + (kstep - 32) * 32 + q * 8;
            }
            half8 hv;
            #pragma unroll
            for (int u = 0; u < 8; ++u) hv[u] = (f16)src[u];
            *(half8*)(wfrag + f * 512 + l * 8) = hv;
        }
        if (tid < 32) {
            int gate = tid >> 3, col = tid & 7;
            int wrow = gate * H_SZ + jb + col;
            bl[tid] = layer ? (p.bih1[wrow] + p.bhh1[wrow])
                            : (p.bih0[wrow] + p.bhh0[wrow]);
        }
        c_lds[tid] = 0.f;   // 512 = 64x8 exactly
    }
    __syncthreads();

    auto ldB = [&](int kg, int nt) -> half8 {
        return *(const half8*)(wfrag + (kg * 2 + nt) * 512 + l * 8);
    };
    auto wtile = [&](int slot, const f32x4& v) {
        *(f32x4*)(P + slot * 256 + n16 * 16 + q * 4) = v;
    };
    auto atile = [&](int slot, f32x4& a) {
        a += *(const f32x4*)(P + slot * 256 + n16 * 16 + q * 4);
    };

    for (int s = 0; s < T_SEQ; ++s) {
        f32x4 acc0[4] = {}, acc1[4] = {};

        if (layer == 0) {
            // -- x part first (no cross-block dependency: hides barrier latency)
            #pragma unroll
            for (int u = 0; u < 2; ++u) {
                int kg = wv * 2 + u;
                int kb = kg * 32 + q * 8;
                half8 b0 = ldB(kg, 0), b1 = ldB(kg, 1);
                #pragma unroll
                for (int mt = 0; mt < 4; ++mt) {
                    const float* ap = p.x + ((size_t)(mt * 16 + n16) * T_SEQ + s) * IN_SZ + kb;
                    f32x4 xa = *(const f32x4*)ap;
                    f32x4 xb = *(const f32x4*)(ap + 4);
                    half8 af;
                    #pragma unroll
                    for (int u2 = 0; u2 < 4; ++u2) { af[u2] = (f16)xa[u2]; af[4 + u2] = (f16)xb[u2]; }
                    acc0[mt] = __builtin_amdgcn_mfma_f32_16x16x32_f16(af, b0, acc0[mt], 0, 0, 0);
                    acc1[mt] = __builtin_amdgcn_mfma_f32_16x16x32_f16(af, b1, acc1[mt], 0, 0, 0);
                }
            }
            // -- wait: own group done s-1; layer1 far enough for ring overwrite
            if (tid == 0) {
                int t0 = 128 * s, t1 = 128 * (s - (RING - 1));
                while (__hip_atomic_load(p.cnt0, __ATOMIC_RELAXED, __HIP_MEMORY_SCOPE_AGENT) < t0)
                    __builtin_amdgcn_s_sleep(1);
                while (__hip_atomic_load(p.cnt1, __ATOMIC_RELAXED, __HIP_MEMORY_SCOPE_AGENT) < t1)
                    __builtin_amdgcn_s_sleep(1);
            }
            __syncthreads();
            __builtin_amdgcn_fence(__ATOMIC_ACQUIRE, "agent");
            // -- recurrent part: h1[s-1]
            if (s > 0) {
                const f16* hp = p.h1ring + (size_t)((s - 1) & (RING - 1)) * (B_SZ * H_SZ);
                #pragma unroll
                for (int u = 0; u < 4; ++u) {
                    int kg = 16 + wv * 4 + u;
                    int kb = (kg - 16) * 32 + q * 8;
                    half8 b0 = ldB(kg, 0), b1 = ldB(kg, 1);
                    #pragma unroll
                    for (int mt = 0; mt < 4; ++mt) {
                        half8 af = *(const half8*)(hp + (size_t)(mt * 16 + n16) * H_SZ + kb);
                        acc0[mt] = __builtin_amdgcn_mfma_f32_16x16x32_f16(af, b0, acc0[mt], 0, 0, 0);
                        acc1[mt] = __builtin_amdgcn_mfma_f32_16x16x32_f16(af, b1, acc1[mt], 0, 0, 0);
                    }
                }
            }
        } else {
            // -- wait: h1[t] published; own group done t-1
            if (tid == 0) {
                int t0 = 128 * (s + 1), t1 = 128 * s;
                while (__hip_atomic_load(p.cnt0, __ATOMIC_RELAXED, __HIP_MEMORY_SCOPE_AGENT) < t0)
                    __builtin_amdgcn_s_sleep(1);
                while (__hip_atomic_load(p.cnt1, __ATOMIC_RELAXED, __HIP_MEMORY_SCOPE_AGENT) < t1)
                    __builtin_amdgcn_s_sleep(1);
            }
            __syncthreads();
            __builtin_amdgcn_fence(__ATOMIC_ACQUIRE, "agent");
            // -- input part: h1[t]
            {
                const f16* hp = p.h1ring + (size_t)(s & (RING - 1)) * (B_SZ * H_SZ);
                #pragma unroll
                for (int u = 0; u < 4; ++u) {
                    int kg = wv * 4 + u;
                    int kb = kg * 32 + q * 8;
                    half8 b0 = ldB(kg, 0), b1 = ldB(kg, 1);
                    #pragma unroll
                    for (int mt = 0; mt < 4; ++mt) {
                        half8 af = *(const half8*)(hp + (size_t)(mt * 16 + n16) * H_SZ + kb);
                        acc0[mt] = __builtin_amdgcn_mfma_f32_16x16x32_f16(af, b0, acc0[mt], 0, 0, 0);
                        acc1[mt] = __builtin_amdgcn_mfma_f32_16x16x32_f16(af, b1, acc1[mt], 0, 0, 0);
                    }
                }
            }
            // -- recurrent part: h2[t-1]
            if (s > 0) {
                const f16* hp = p.h2all + (size_t)(s - 1) * (B_SZ * H_SZ);
                #pragma unroll
                for (int u = 0; u < 4; ++u) {
                    int kg = 32 + wv * 4 + u;
                    int kb = (kg - 32) * 32 + q * 8;
                    half8 b0 = ldB(kg, 0), b1 = ldB(kg, 1);
                    #pragma unroll
                    for (int mt = 0; mt < 4; ++mt) {
                        half8 af = *(const half8*)(hp + (size_t)(mt * 16 + n16) * H_SZ + kb);
                        acc0[mt] = __builtin_amdgcn_mfma_f32_16x16x32_f16(af, b0, acc0[mt], 0, 0, 0);
                        acc1[mt] = __builtin_amdgcn_mfma_f32_16x16x32_f16(af, b1, acc1[mt], 0, 0, 0);
                    }
                }
            }
        }

        // ---- k-slice reduction tree (8 waves -> wave0, 16KB peak LDS) ----
        if (wv >= 4) {
            #pragma unroll
            for (int mt = 0; mt < 4; ++mt) wtile((wv - 4) * 4 + mt, acc0[mt]);
        }
        __syncthreads();
        if (wv < 4) {
            #pragma unroll
            for (int mt = 0; mt < 4; ++mt) atile(wv * 4 + mt, acc0[mt]);
        }
        __syncthreads();
        if (wv >= 4) {
            #pragma unroll
            for (int mt = 0; mt < 4; ++mt) wtile((wv - 4) * 4 + mt, acc1[mt]);
        }
        __syncthreads();
        if (wv < 4) {
            #pragma unroll
            for (int mt = 0; mt < 4; ++mt) atile(wv * 4 + mt, acc1[mt]);
        }
        __syncthreads();
        if (wv == 2 || wv == 3) {
            #pragma unroll
            for (int mt = 0; mt < 4; ++mt) {
                wtile((wv - 2) * 8 + mt, acc0[mt]);
                wtile((wv - 2) * 8 + 4 + mt, acc1[mt]);
            }
        }
        __syncthreads();
        if (wv < 2) {
            #pragma unroll
            for (int mt = 0; mt < 4; ++mt) {
                atile(wv * 8 + mt, acc0[mt]);
                atile(wv * 8 + 4 + mt, acc1[mt]);
            }
        }
        __syncthreads();
        if (wv == 1) {
            #pragma unroll
            for (int mt = 0; mt < 4; ++mt) {
                wtile(mt, acc0[mt]);
                wtile(4 + mt, acc1[mt]);
            }
        }
        __syncthreads();
        if (wv == 0) {
            #pragma unroll
            for (int mt = 0; mt < 4; ++mt) {
                atile(mt, acc0[mt]);
                atile(4 + mt, acc1[mt]);
            }
            #pragma unroll
            for (int mt = 0; mt < 4; ++mt) {
                wtile(mt, acc0[mt]);
                wtile(4 + mt, acc1[mt]);
            }
        }
        __syncthreads();

        // ---- epilogue: all 512 threads, one (b, col) each ----
        {
            int b = tid >> 3, col = tid & 7;
            int mt = b >> 4, r = b & 15;
            float iv = P[mt * 256 + col * 16 + r]             + bl[col];
            float fv = P[mt * 256 + (col + 8) * 16 + r]       + bl[8 + col];
            float gv = P[(4 + mt) * 256 + col * 16 + r]       + bl[16 + col];
            float ov = P[(4 + mt) * 256 + (col + 8) * 16 + r] + bl[24 + col];
            float co = c_lds[tid];
            float ii = sigf(iv), ff = sigf(fv), gg = tanhfast(gv), oo = sigf(ov);
            float cn = ff * co + ii * gg;
            float hn = oo * tanhfast(cn);
            c_lds[tid] = cn;
            f16* dst = layer ? (p.h2all + (size_t)s * (B_SZ * H_SZ))
                             : (p.h1ring + (size_t)(s & (RING - 1)) * (B_SZ * H_SZ));
            dst[(size_t)b * H_SZ + jb + col] = (f16)hn;
        }
        __threadfence();      // drain every wave's h stores to agent scope
        __syncthreads();
        if (tid == 0)
            __hip_atomic_fetch_add(layer ? p.cnt1 : p.cnt0, 1,
                                   __ATOMIC_RELEASE, __HIP_MEMORY_SCOPE_AGENT);
    }
}

// ---------------------------------------------------------------------------
// Output projection: out[b,t] = h2[t,b,:] . w_out + b_out
// ---------------------------------------------------------------------------
__global__ __launch_bounds__(256) void gemv_kernel(
    const f16* __restrict__ h2all, const float* __restrict__ wout,
    const float* __restrict__ bout, float* __restrict__ out)
{
    int t = blockIdx.x;
    int wave = threadIdx.x >> 6, lane = threadIdx.x & 63;
    float w[16];
    #pragma unroll
    for (int u = 0; u < 16; ++u) w[u] = wout[lane * 16 + u];
    float b0 = bout[0];
    for (int b = wave; b < B_SZ; b += 4) {
        const f16* hp = h2all + ((size_t)t * B_SZ + b) * H_SZ + lane * 16;
        float sum = 0.f;
        #pragma unroll
        for (int u = 0; u < 16; ++u) sum += (float)hp[u] * w[u];
        #pragma unroll
        for (int off = 32; off; off >>= 1) sum += __shfl_down(sum, off, 64);
        if (lane == 0) out[(size_t)b * T_SEQ + t] = sum + b0;
    }
}

// ---------------------------------------------------------------------------
extern "C" void kernel_launch(void* const* d_in, const int* in_sizes, int n_in,
                              void* d_out, int out_size, void* d_ws, size_t ws_size,
                              hipStream_t stream)
{
    const float* x    = (const float*)d_in[0];
    const float* wih0 = (const float*)d_in[1];
    const float* whh0 = (const float*)d_in[2];
    const float* bih0 = (const float*)d_in[3];
    const float* bhh0 = (const float*)d_in[4];
    const float* wih1 = (const float*)d_in[5];
    const float* whh1 = (const float*)d_in[6];
    const float* bih1 = (const float*)d_in[7];
    const float* bhh1 = (const float*)d_in[8];
    const float* wout = (const float*)d_in[9];
    const float* bout = (const float*)d_in[10];
    float* out = (float*)d_out;

    char* ws = (char*)d_ws;
    size_t off = 0;
    auto alloc = [&](size_t bytes) -> void* {
        void* pp = ws + off;
        off += (bytes + 255) & ~(size_t)255;
        return pp;
    };
    f16* h1ring = (f16*)alloc((size_t)RING * B_SZ * H_SZ * 2);    // 1 MB
    f16* h2all  = (f16*)alloc((size_t)T_SEQ * B_SZ * H_SZ * 2);   // 67 MB
    int* cnts   = (int*)alloc(256);

    (void)hipMemsetAsync(cnts, 0, 256, stream);   // counters restart at 0 every replay

    Params pa;
    pa.x = x;
    pa.wih0 = wih0; pa.whh0 = whh0; pa.bih0 = bih0; pa.bhh0 = bhh0;
    pa.wih1 = wih1; pa.whh1 = whh1; pa.bih1 = bih1; pa.bhh1 = bhh1;
    pa.h1ring = h1ring; pa.h2all = h2all;
    pa.cnt0 = cnts; pa.cnt1 = cnts + 32;

    (void)hipFuncSetAttribute((const void*)persist_kernel,
                              hipFuncAttributeMaxDynamicSharedMemorySize, SMEM_BYTES);

    // Cooperative launch guarantees co-residency; under graph capture fall back
    // to a plain launch (identical kernel; LDS of 146KB forces 1 block/CU and
    // grid == CU count, so all 256 blocks are co-resident by construction).
    hipStreamCaptureStatus cap = hipStreamCaptureStatusNone;
    (void)hipStreamIsCapturing(stream, &cap);
    bool launched = false;
    if (cap == hipStreamCaptureStatusNone) {
        void* kargs[] = { (void*)&pa };
        if (hipLaunchCooperativeKernel((const void*)persist_kernel, dim3(NBLK), dim3(NTHR),
                                       kargs, SMEM_BYTES, stream) == hipSuccess)
            launched = true;
    }
    if (!launched)
        persist_kernel<<<NBLK, NTHR, SMEM_BYTES, stream>>>(pa);

    gemv_kernel<<<T_SEQ, 256, 0, stream>>>(h2all, wout, bout, out);
}

// Round 4
// 13897.987 us; speedup vs baseline: 2.8877x; 2.8877x over previous
//
#include <hip/hip_runtime.h>

// Problem dims (fixed by reference)
#define T_SEQ 512
#define B_SZ  64
#define IN_SZ 512
#define H_SZ  1024
#define NBLK  256   // 128 blocks layer0 + 128 blocks layer1, 1 block/CU (LDS-forced)
#define NTHR  512   // 8 waves
#define RING  8     // h1 ring depth (layer-0 max lead over layer-1)
#define FSTRIDE 32  // flag stride in ints (128B: one flag per cacheline)

typedef _Float16 f16;
typedef _Float16 half8 __attribute__((ext_vector_type(8)));
typedef float    f32x4 __attribute__((ext_vector_type(4)));

// LDS layout (dynamic): wfrag [0,128K) | partial tiles [128K,+16K) | c [+2K) | bias [+128B)
#define SM_WFRAG 0
#define SM_PART  131072
#define SM_C     (131072 + 16384)
#define SM_BIAS  (131072 + 16384 + 2048)
#define SMEM_BYTES (131072 + 16384 + 2048 + 128)

struct Params {
    const float *x;
    const float *wih0, *whh0, *bih0, *bhh0;
    const float *wih1, *whh1, *bih1, *bhh1;
    f16 *h1ring;   // [RING][B][H]
    f16 *h2all;    // [T][B][H]
    int *flags0, *flags1;   // [128] step-completion flags, FSTRIDE ints apart
};

__device__ __forceinline__ float sigf(float x)     { return 1.f / (1.f + __expf(-x)); }
__device__ __forceinline__ float tanhfast(float x) { return 2.f / (1.f + __expf(-2.f * x)) - 1.f; }

// ---------------------------------------------------------------------------
// Persistent 2-layer LSTM. blocks 0..127: layer 0 (free-runs ahead, bounded by
// RING). blocks 128..255: layer 1. Each block owns 8 h-columns (32 gate rows),
// weights live in LDS in MFMA-B fragment order.
// Sync: per-block release flags (own cacheline) + wave-0 parallel poll.
// h published via agent-scope atomic ushort stores (write-through to LLC).
// ---------------------------------------------------------------------------
__global__ __launch_bounds__(NTHR, 2) void persist_kernel(Params p)
{
    extern __shared__ char smem[];
    f16*   wfrag = (f16*)(smem + SM_WFRAG);
    float* P     = (float*)(smem + SM_PART);   // 16 slots x 256 f32, lane-dump layout
    float* c_lds = (float*)(smem + SM_C);      // [64][8] cell state, persistent
    float* bl    = (float*)(smem + SM_BIAS);   // [4 gates][8 cols]

    const int tid = threadIdx.x;
    const int l   = tid & 63, wv = tid >> 6;
    const int n16 = l & 15,  q  = l >> 4;
    const int layer = blockIdx.x >> 7;
    const int bid   = blockIdx.x & 127;
    const int jb    = bid * 8;

    // ---- one-time staging: weights fp32 -> f16 fragments in LDS ----
    {
        const int gate0 = n16 >> 3, c8 = n16 & 7;
        const int nfrag = layer ? 128 : 96;   // (K/32)*2 nt
        for (int f = wv; f < nfrag; f += 8) {
            int kstep = f >> 1, nt = f & 1;
            int wrow = (nt * 2 + gate0) * H_SZ + jb + c8;
            const float* src;
            if (layer == 0) {
                src = (kstep < 16) ? p.wih0 + (size_t)wrow * IN_SZ + kstep * 32 + q * 8
                                   : p.whh0 + (size_t)wrow * H_SZ + (kstep - 16) * 32 + q * 8;
            } else {
                src = (kstep < 32) ? p.wih1 + (size_t)wrow * H_SZ + kstep * 32 + q * 8
                                   : p.whh1 + (size_t)wrow * H_SZ + (kstep - 32) * 32 + q * 8;
            }
            half8 hv;
            #pragma unroll
            for (int u = 0; u < 8; ++u) hv[u] = (f16)src[u];
            *(half8*)(wfrag + f * 512 + l * 8) = hv;
        }
        if (tid < 32) {
            int gate = tid >> 3, col = tid & 7;
            int wrow = gate * H_SZ + jb + col;
            bl[tid] = layer ? (p.bih1[wrow] + p.bhh1[wrow])
                            : (p.bih0[wrow] + p.bhh0[wrow]);
        }
        c_lds[tid] = 0.f;   // 512 = 64x8 exactly
    }
    __syncthreads();

    auto ldB = [&](int kg, int nt) -> half8 {
        return *(const half8*)(wfrag + (kg * 2 + nt) * 512 + l * 8);
    };
    // lane-dump tile layout: conflict-free contiguous b128 per wave
    auto wtile = [&](int slot, const f32x4& v) {
        *(f32x4*)(P + slot * 256 + l * 4) = v;
    };
    auto atile = [&](int slot, f32x4& a) {
        a += *(const f32x4*)(P + slot * 256 + l * 4);
    };
    int* myflag = (layer ? p.flags1 : p.flags0) + bid * FSTRIDE;

    for (int s = 0; s < T_SEQ; ++s) {
        f32x4 acc0[4] = {}, acc1[4] = {};

        if (layer == 0) {
            // -- x part first (no cross-block dependency: overlaps the wait)
            #pragma unroll
            for (int u = 0; u < 2; ++u) {
                int kg = wv * 2 + u;
                int kb = kg * 32 + q * 8;
                half8 b0 = ldB(kg, 0), b1 = ldB(kg, 1);
                #pragma unroll
                for (int mt = 0; mt < 4; ++mt) {
                    const float* ap = p.x + ((size_t)(mt * 16 + n16) * T_SEQ + s) * IN_SZ + kb;
                    f32x4 xa = *(const f32x4*)ap;
                    f32x4 xb = *(const f32x4*)(ap + 4);
                    half8 af;
                    #pragma unroll
                    for (int u2 = 0; u2 < 4; ++u2) { af[u2] = (f16)xa[u2]; af[4 + u2] = (f16)xb[u2]; }
                    acc0[mt] = __builtin_amdgcn_mfma_f32_16x16x32_f16(af, b0, acc0[mt], 0, 0, 0);
                    acc1[mt] = __builtin_amdgcn_mfma_f32_16x16x32_f16(af, b1, acc1[mt], 0, 0, 0);
                }
            }
        }

        // ---- wait: parallel poll of per-block flags (wave 0 only) ----
        {
            int tA = layer ? (s + 1) : s;          // flags0 target
            int tB = layer ? s : (s - (RING - 1)); // flags1 target
            if (wv == 0) {
                const int* fA0 = p.flags0 + l * FSTRIDE;
                const int* fA1 = p.flags0 + (64 + l) * FSTRIDE;
                const int* fB0 = p.flags1 + l * FSTRIDE;
                const int* fB1 = p.flags1 + (64 + l) * FSTRIDE;
                bool d0 = false, d1 = false, d2 = false, d3 = false;
                while (true) {
                    if (!d0) d0 = __hip_atomic_load(fA0, __ATOMIC_RELAXED, __HIP_MEMORY_SCOPE_AGENT) >= tA;
                    if (!d1) d1 = __hip_atomic_load(fA1, __ATOMIC_RELAXED, __HIP_MEMORY_SCOPE_AGENT) >= tA;
                    if (!d2) d2 = __hip_atomic_load(fB0, __ATOMIC_RELAXED, __HIP_MEMORY_SCOPE_AGENT) >= tB;
                    if (!d3) d3 = __hip_atomic_load(fB1, __ATOMIC_RELAXED, __HIP_MEMORY_SCOPE_AGENT) >= tB;
                    if (__all(d0 && d1 && d2 && d3)) break;
                    __builtin_amdgcn_s_sleep(2);
                }
            }
            __syncthreads();
            __builtin_amdgcn_fence(__ATOMIC_ACQUIRE, "agent");
        }

        if (layer == 0) {
            // -- recurrent part: h1[s-1]
            if (s > 0) {
                const f16* hp = p.h1ring + (size_t)((s - 1) & (RING - 1)) * (B_SZ * H_SZ);
                #pragma unroll
                for (int u = 0; u < 4; ++u) {
                    int kg = 16 + wv * 4 + u;
                    int kb = (kg - 16) * 32 + q * 8;
                    half8 b0 = ldB(kg, 0), b1 = ldB(kg, 1);
                    #pragma unroll
                    for (int mt = 0; mt < 4; ++mt) {
                        half8 af = *(const half8*)(hp + (size_t)(mt * 16 + n16) * H_SZ + kb);
                        acc0[mt] = __builtin_amdgcn_mfma_f32_16x16x32_f16(af, b0, acc0[mt], 0, 0, 0);
                        acc1[mt] = __builtin_amdgcn_mfma_f32_16x16x32_f16(af, b1, acc1[mt], 0, 0, 0);
                    }
                }
            }
        } else {
            // -- input part: h1[s]
            {
                const f16* hp = p.h1ring + (size_t)(s & (RING - 1)) * (B_SZ * H_SZ);
                #pragma unroll
                for (int u = 0; u < 4; ++u) {
                    int kg = wv * 4 + u;
                    int kb = kg * 32 + q * 8;
                    half8 b0 = ldB(kg, 0), b1 = ldB(kg, 1);
                    #pragma unroll
                    for (int mt = 0; mt < 4; ++mt) {
                        half8 af = *(const half8*)(hp + (size_t)(mt * 16 + n16) * H_SZ + kb);
                        acc0[mt] = __builtin_amdgcn_mfma_f32_16x16x32_f16(af, b0, acc0[mt], 0, 0, 0);
                        acc1[mt] = __builtin_amdgcn_mfma_f32_16x16x32_f16(af, b1, acc1[mt], 0, 0, 0);
                    }
                }
            }
            // -- recurrent part: h2[s-1]
            if (s > 0) {
                const f16* hp = p.h2all + (size_t)(s - 1) * (B_SZ * H_SZ);
                #pragma unroll
                for (int u = 0; u < 4; ++u) {
                    int kg = 32 + wv * 4 + u;
                    int kb = (kg - 32) * 32 + q * 8;
                    half8 b0 = ldB(kg, 0), b1 = ldB(kg, 1);
                    #pragma unroll
                    for (int mt = 0; mt < 4; ++mt) {
                        half8 af = *(const half8*)(hp + (size_t)(mt * 16 + n16) * H_SZ + kb);
                        acc0[mt] = __builtin_amdgcn_mfma_f32_16x16x32_f16(af, b0, acc0[mt], 0, 0, 0);
                        acc1[mt] = __builtin_amdgcn_mfma_f32_16x16x32_f16(af, b1, acc1[mt], 0, 0, 0);
                    }
                }
            }
        }

        // ---- k-slice reduction tree (8 waves -> wave0, 16KB peak LDS) ----
        if (wv >= 4) {
            #pragma unroll
            for (int mt = 0; mt < 4; ++mt) wtile((wv - 4) * 4 + mt, acc0[mt]);
        }
        __syncthreads();
        if (wv < 4) {
            #pragma unroll
            for (int mt = 0; mt < 4; ++mt) atile(wv * 4 + mt, acc0[mt]);
        }
        __syncthreads();
        if (wv >= 4) {
            #pragma unroll
            for (int mt = 0; mt < 4; ++mt) wtile((wv - 4) * 4 + mt, acc1[mt]);
        }
        __syncthreads();
        if (wv < 4) {
            #pragma unroll
            for (int mt = 0; mt < 4; ++mt) atile(wv * 4 + mt, acc1[mt]);
        }
        __syncthreads();
        if (wv == 2 || wv == 3) {
            #pragma unroll
            for (int mt = 0; mt < 4; ++mt) {
                wtile((wv - 2) * 8 + mt, acc0[mt]);
                wtile((wv - 2) * 8 + 4 + mt, acc1[mt]);
            }
        }
        __syncthreads();
        if (wv < 2) {
            #pragma unroll
            for (int mt = 0; mt < 4; ++mt) {
                atile(wv * 8 + mt, acc0[mt]);
                atile(wv * 8 + 4 + mt, acc1[mt]);
            }
        }
        __syncthreads();
        if (wv == 1) {
            #pragma unroll
            for (int mt = 0; mt < 4; ++mt) {
                wtile(mt, acc0[mt]);
                wtile(4 + mt, acc1[mt]);
            }
        }
        __syncthreads();
        if (wv == 0) {
            #pragma unroll
            for (int mt = 0; mt < 4; ++mt) {
                atile(mt, acc0[mt]);
                atile(4 + mt, acc1[mt]);
            }
            #pragma unroll
            for (int mt = 0; mt < 4; ++mt) {
                wtile(mt, acc0[mt]);
                wtile(4 + mt, acc1[mt]);
            }
        }
        __syncthreads();

        // ---- epilogue: all 512 threads, one (b, col) each ----
        {
            int b = tid >> 3, col = tid & 7;
            int mt = b >> 4, r = b & 15;
            int base = (r >> 2) * 64 + (r & 3);   // lane-dump index of (r, c=0)
            float iv = P[mt * 256 + base + col * 4]             + bl[col];
            float fv = P[mt * 256 + base + (col + 8) * 4]       + bl[8 + col];
            float gv = P[(4 + mt) * 256 + base + col * 4]       + bl[16 + col];
            float ov = P[(4 + mt) * 256 + base + (col + 8) * 4] + bl[24 + col];
            float co = c_lds[tid];
            float ii = sigf(iv), ff = sigf(fv), gg = tanhfast(gv), oo = sigf(ov);
            float cn = ff * co + ii * gg;
            float hn = oo * tanhfast(cn);
            c_lds[tid] = cn;
            f16* dst = layer ? (p.h2all + (size_t)s * (B_SZ * H_SZ))
                             : (p.h1ring + (size_t)(s & (RING - 1)) * (B_SZ * H_SZ));
            // write-through to coherent point (LLC): agent-scope atomic store
            unsigned short hb = __builtin_bit_cast(unsigned short, (f16)hn);
            __hip_atomic_store((unsigned short*)&dst[(size_t)b * H_SZ + jb + col], hb,
                               __ATOMIC_RELAXED, __HIP_MEMORY_SCOPE_AGENT);
        }
        __syncthreads();   // barrier drains vmcnt: all h stores globally visible
        if (tid == 0)
            __hip_atomic_store(myflag, s + 1, __ATOMIC_RELEASE, __HIP_MEMORY_SCOPE_AGENT);
    }
}

// ---------------------------------------------------------------------------
// Output projection: out[b,t] = h2[t,b,:] . w_out + b_out
// ---------------------------------------------------------------------------
__global__ __launch_bounds__(256) void gemv_kernel(
    const f16* __restrict__ h2all, const float* __restrict__ wout,
    const float* __restrict__ bout, float* __restrict__ out)
{
    int t = blockIdx.x;
    int wave = threadIdx.x >> 6, lane = threadIdx.x & 63;
    float w[16];
    #pragma unroll
    for (int u = 0; u < 16; ++u) w[u] = wout[lane * 16 + u];
    float b0 = bout[0];
    for (int b = wave; b < B_SZ; b += 4) {
        const f16* hp = h2all + ((size_t)t * B_SZ + b) * H_SZ + lane * 16;
        float sum = 0.f;
        #pragma unroll
        for (int u = 0; u < 16; ++u) sum += (float)hp[u] * w[u];
        #pragma unroll
        for (int off = 32; off; off >>= 1) sum += __shfl_down(sum, off, 64);
        if (lane == 0) out[(size_t)b * T_SEQ + t] = sum + b0;
    }
}

// ---------------------------------------------------------------------------
extern "C" void kernel_launch(void* const* d_in, const int* in_sizes, int n_in,
                              void* d_out, int out_size, void* d_ws, size_t ws_size,
                              hipStream_t stream)
{
    const float* x    = (const float*)d_in[0];
    const float* wih0 = (const float*)d_in[1];
    const float* whh0 = (const float*)d_in[2];
    const float* bih0 = (const float*)d_in[3];
    const float* bhh0 = (const float*)d_in[4];
    const float* wih1 = (const float*)d_in[5];
    const float* whh1 = (const float*)d_in[6];
    const float* bih1 = (const float*)d_in[7];
    const float* bhh1 = (const float*)d_in[8];
    const float* wout = (const float*)d_in[9];
    const float* bout = (const float*)d_in[10];
    float* out = (float*)d_out;

    char* ws = (char*)d_ws;
    size_t off = 0;
    auto alloc = [&](size_t bytes) -> void* {
        void* pp = ws + off;
        off += (bytes + 255) & ~(size_t)255;
        return pp;
    };
    f16* h1ring = (f16*)alloc((size_t)RING * B_SZ * H_SZ * 2);    // 1 MB
    f16* h2all  = (f16*)alloc((size_t)T_SEQ * B_SZ * H_SZ * 2);   // 67 MB
    int* flags  = (int*)alloc(2 * 128 * FSTRIDE * 4);             // 32 KB

    (void)hipMemsetAsync(flags, 0, 2 * 128 * FSTRIDE * 4, stream);  // restart flags each replay

    Params pa;
    pa.x = x;
    pa.wih0 = wih0; pa.whh0 = whh0; pa.bih0 = bih0; pa.bhh0 = bhh0;
    pa.wih1 = wih1; pa.whh1 = whh1; pa.bih1 = bih1; pa.bhh1 = bhh1;
    pa.h1ring = h1ring; pa.h2all = h2all;
    pa.flags0 = flags; pa.flags1 = flags + 128 * FSTRIDE;

    (void)hipFuncSetAttribute((const void*)persist_kernel,
                              hipFuncAttributeMaxDynamicSharedMemorySize, SMEM_BYTES);

    // Cooperative launch guarantees co-residency; under graph capture fall back
    // to a plain launch (identical kernel; 146KB LDS forces 1 block/CU and
    // grid == CU count, so all 256 blocks are co-resident by construction).
    hipStreamCaptureStatus cap = hipStreamCaptureStatusNone;
    (void)hipStreamIsCapturing(stream, &cap);
    bool launched = false;
    if (cap == hipStreamCaptureStatusNone) {
        void* kargs[] = { (void*)&pa };
        if (hipLaunchCooperativeKernel((const void*)persist_kernel, dim3(NBLK), dim3(NTHR),
                                       kargs, SMEM_BYTES, stream) == hipSuccess)
            launched = true;
    }
    if (!launched)
        persist_kernel<<<NBLK, NTHR, SMEM_BYTES, stream>>>(pa);

    gemv_kernel<<<T_SEQ, 256, 0, stream>>>(h2all, wout, bout, out);
}

// Round 5
// 6549.677 us; speedup vs baseline: 6.1275x; 2.1219x over previous
//
#include <hip/hip_runtime.h>

// Problem dims (fixed by reference)
#define T_SEQ 512
#define B_SZ  64
#define IN_SZ 512
#define H_SZ  1024
#define NBLK  256   // 128 blocks layer0 + 128 blocks layer1, 1 block/CU (LDS-forced)
#define NTHR  512   // 8 waves
#define FSTRIDE 32  // flag stride in ints (128B: one flag per cacheline)

typedef _Float16 f16;
typedef _Float16 half8 __attribute__((ext_vector_type(8)));
typedef float    f32x4 __attribute__((ext_vector_type(4)));

// LDS layout (dynamic): wfrag [0,128K) | partial tiles [128K,+16K) | c [+2K) | bias [+128B)
#define SM_WFRAG 0
#define SM_PART  131072
#define SM_C     (131072 + 16384)
#define SM_BIAS  (131072 + 16384 + 2048)
#define SMEM_BYTES (131072 + 16384 + 2048 + 128)

struct Params {
    const float *x;
    const float *wih0, *whh0, *bih0, *bhh0;
    const float *wih1, *whh1, *bih1, *bhh1;
    f16 *h1all;    // [T][B][H]  rotating addresses: no consumer cache ever holds them stale
    f16 *h2all;    // [T][B][H]
    int *flags0, *flags1;   // [128] step-completion flags, FSTRIDE ints apart
};

__device__ __forceinline__ float sigf(float x)     { return 1.f / (1.f + __expf(-x)); }
__device__ __forceinline__ float tanhfast(float x) { return 2.f / (1.f + __expf(-2.f * x)) - 1.f; }

// ---------------------------------------------------------------------------
// Persistent 2-layer LSTM, fence-free coherence:
//  - producers publish h via agent-scope write-through atomic ushort stores
//    (bypass producer L2, land at LLC), then release-store a per-block flag;
//  - consumers poll flags (agent-scope loads), then read h with PLAIN cached
//    loads — every h address is written exactly once, so no stale line can
//    exist in any consumer cache; per-XCD L2 dedups the 128KB broadcast.
// No per-step fences -> L2 contents survive -> x/h reads are L2-served.
// ---------------------------------------------------------------------------
__global__ __launch_bounds__(NTHR, 2) void persist_kernel(Params p)
{
    extern __shared__ char smem[];
    f16*   wfrag = (f16*)(smem + SM_WFRAG);
    float* P     = (float*)(smem + SM_PART);   // 16 slots x 256 f32, lane-dump layout
    float* c_lds = (float*)(smem + SM_C);      // [64][8] cell state, persistent
    float* bl    = (float*)(smem + SM_BIAS);   // [4 gates][8 cols]

    const int tid = threadIdx.x;
    const int l   = tid & 63, wv = tid >> 6;
    const int n16 = l & 15,  q  = l >> 4;
    const int layer = blockIdx.x >> 7;
    const int bid   = blockIdx.x & 127;
    const int jb    = bid * 8;

    // ---- one-time staging: weights fp32 -> f16 fragments in LDS ----
    {
        const int gate0 = n16 >> 3, c8 = n16 & 7;
        const int nfrag = layer ? 128 : 96;   // (K/32)*2 nt
        for (int f = wv; f < nfrag; f += 8) {
            int kstep = f >> 1, nt = f & 1;
            int wrow = (nt * 2 + gate0) * H_SZ + jb + c8;
            const float* src;
            if (layer == 0) {
                src = (kstep < 16) ? p.wih0 + (size_t)wrow * IN_SZ + kstep * 32 + q * 8
                                   : p.whh0 + (size_t)wrow * H_SZ + (kstep - 16) * 32 + q * 8;
            } else {
                src = (kstep < 32) ? p.wih1 + (size_t)wrow * H_SZ + kstep * 32 + q * 8
                                   : p.whh1 + (size_t)wrow * H_SZ + (kstep - 32) * 32 + q * 8;
            }
            half8 hv;
            #pragma unroll
            for (int u = 0; u < 8; ++u) hv[u] = (f16)src[u];
            *(half8*)(wfrag + f * 512 + l * 8) = hv;
        }
        if (tid < 32) {
            int gate = tid >> 3, col = tid & 7;
            int wrow = gate * H_SZ + jb + col;
            bl[tid] = layer ? (p.bih1[wrow] + p.bhh1[wrow])
                            : (p.bih0[wrow] + p.bhh0[wrow]);
        }
        c_lds[tid] = 0.f;   // 512 = 64x8 exactly
    }
    __syncthreads();

    auto ldB = [&](int kg, int nt) -> half8 {
        return *(const half8*)(wfrag + (kg * 2 + nt) * 512 + l * 8);
    };
    // lane-dump tile layout: conflict-free contiguous b128 per wave
    auto wtile = [&](int slot, const f32x4& v) {
        *(f32x4*)(P + slot * 256 + l * 4) = v;
    };
    auto atile = [&](int slot, f32x4& a) {
        a += *(const f32x4*)(P + slot * 256 + l * 4);
    };
    int* myflag = (layer ? p.flags1 : p.flags0) + bid * FSTRIDE;

    for (int s = 0; s < T_SEQ; ++s) {
        f32x4 acc0[4] = {}, acc1[4] = {};

        if (layer == 0) {
            // -- x part first (no cross-block dependency: overlaps the wait)
            #pragma unroll
            for (int u = 0; u < 2; ++u) {
                int kg = wv * 2 + u;
                int kb = kg * 32 + q * 8;
                half8 b0 = ldB(kg, 0), b1 = ldB(kg, 1);
                #pragma unroll
                for (int mt = 0; mt < 4; ++mt) {
                    const float* ap = p.x + ((size_t)(mt * 16 + n16) * T_SEQ + s) * IN_SZ + kb;
                    f32x4 xa = *(const f32x4*)ap;
                    f32x4 xb = *(const f32x4*)(ap + 4);
                    half8 af;
                    #pragma unroll
                    for (int u2 = 0; u2 < 4; ++u2) { af[u2] = (f16)xa[u2]; af[4 + u2] = (f16)xb[u2]; }
                    acc0[mt] = __builtin_amdgcn_mfma_f32_16x16x32_f16(af, b0, acc0[mt], 0, 0, 0);
                    acc1[mt] = __builtin_amdgcn_mfma_f32_16x16x32_f16(af, b1, acc1[mt], 0, 0, 0);
                }
            }
            // ---- wait: own group finished step s-1 (h1[s-1] published) ----
            if (s > 0) {
                if (wv == 0) {
                    const int* fA0 = p.flags0 + l * FSTRIDE;
                    const int* fA1 = p.flags0 + (64 + l) * FSTRIDE;
                    bool d0 = false, d1 = false;
                    while (true) {
                        if (!d0) d0 = __hip_atomic_load(fA0, __ATOMIC_RELAXED, __HIP_MEMORY_SCOPE_AGENT) >= s;
                        if (!d1) d1 = __hip_atomic_load(fA1, __ATOMIC_RELAXED, __HIP_MEMORY_SCOPE_AGENT) >= s;
                        if (__all(d0 && d1)) break;
                        __builtin_amdgcn_s_sleep(1);
                    }
                }
                __syncthreads();
                // -- recurrent part: h1[s-1] (plain cached loads, fresh addresses)
                const f16* hp = p.h1all + (size_t)(s - 1) * (B_SZ * H_SZ);
                #pragma unroll
                for (int u = 0; u < 4; ++u) {
                    int kg = 16 + wv * 4 + u;
                    int kb = (kg - 16) * 32 + q * 8;
                    half8 b0 = ldB(kg, 0), b1 = ldB(kg, 1);
                    #pragma unroll
                    for (int mt = 0; mt < 4; ++mt) {
                        half8 af = *(const half8*)(hp + (size_t)(mt * 16 + n16) * H_SZ + kb);
                        acc0[mt] = __builtin_amdgcn_mfma_f32_16x16x32_f16(af, b0, acc0[mt], 0, 0, 0);
                        acc1[mt] = __builtin_amdgcn_mfma_f32_16x16x32_f16(af, b1, acc1[mt], 0, 0, 0);
                    }
                }
            }
        } else {
            // ---- wait: h1[s] published; own group finished s-1 ----
            {
                if (wv == 0) {
                    const int* fA0 = p.flags0 + l * FSTRIDE;
                    const int* fA1 = p.flags0 + (64 + l) * FSTRIDE;
                    const int* fB0 = p.flags1 + l * FSTRIDE;
                    const int* fB1 = p.flags1 + (64 + l) * FSTRIDE;
                    int tA = s + 1, tB = s;
                    bool d0 = false, d1 = false, d2 = false, d3 = false;
                    while (true) {
                        if (!d0) d0 = __hip_atomic_load(fA0, __ATOMIC_RELAXED, __HIP_MEMORY_SCOPE_AGENT) >= tA;
                        if (!d1) d1 = __hip_atomic_load(fA1, __ATOMIC_RELAXED, __HIP_MEMORY_SCOPE_AGENT) >= tA;
                        if (!d2) d2 = __hip_atomic_load(fB0, __ATOMIC_RELAXED, __HIP_MEMORY_SCOPE_AGENT) >= tB;
                        if (!d3) d3 = __hip_atomic_load(fB1, __ATOMIC_RELAXED, __HIP_MEMORY_SCOPE_AGENT) >= tB;
                        if (__all(d0 && d1 && d2 && d3)) break;
                        __builtin_amdgcn_s_sleep(1);
                    }
                }
                __syncthreads();
            }
            // -- input part: h1[s]
            {
                const f16* hp = p.h1all + (size_t)s * (B_SZ * H_SZ);
                #pragma unroll
                for (int u = 0; u < 4; ++u) {
                    int kg = wv * 4 + u;
                    int kb = kg * 32 + q * 8;
                    half8 b0 = ldB(kg, 0), b1 = ldB(kg, 1);
                    #pragma unroll
                    for (int mt = 0; mt < 4; ++mt) {
                        half8 af = *(const half8*)(hp + (size_t)(mt * 16 + n16) * H_SZ + kb);
                        acc0[mt] = __builtin_amdgcn_mfma_f32_16x16x32_f16(af, b0, acc0[mt], 0, 0, 0);
                        acc1[mt] = __builtin_amdgcn_mfma_f32_16x16x32_f16(af, b1, acc1[mt], 0, 0, 0);
                    }
                }
            }
            // -- recurrent part: h2[s-1]
            if (s > 0) {
                const f16* hp = p.h2all + (size_t)(s - 1) * (B_SZ * H_SZ);
                #pragma unroll
                for (int u = 0; u < 4; ++u) {
                    int kg = 32 + wv * 4 + u;
                    int kb = (kg - 32) * 32 + q * 8;
                    half8 b0 = ldB(kg, 0), b1 = ldB(kg, 1);
                    #pragma unroll
                    for (int mt = 0; mt < 4; ++mt) {
                        half8 af = *(const half8*)(hp + (size_t)(mt * 16 + n16) * H_SZ + kb);
                        acc0[mt] = __builtin_amdgcn_mfma_f32_16x16x32_f16(af, b0, acc0[mt], 0, 0, 0);
                        acc1[mt] = __builtin_amdgcn_mfma_f32_16x16x32_f16(af, b1, acc1[mt], 0, 0, 0);
                    }
                }
            }
        }

        // ---- k-slice reduction tree (8 waves -> wave0, 16KB peak LDS) ----
        if (wv >= 4) {
            #pragma unroll
            for (int mt = 0; mt < 4; ++mt) wtile((wv - 4) * 4 + mt, acc0[mt]);
        }
        __syncthreads();
        if (wv < 4) {
            #pragma unroll
            for (int mt = 0; mt < 4; ++mt) atile(wv * 4 + mt, acc0[mt]);
        }
        __syncthreads();
        if (wv >= 4) {
            #pragma unroll
            for (int mt = 0; mt < 4; ++mt) wtile((wv - 4) * 4 + mt, acc1[mt]);
        }
        __syncthreads();
        if (wv < 4) {
            #pragma unroll
            for (int mt = 0; mt < 4; ++mt) atile(wv * 4 + mt, acc1[mt]);
        }
        __syncthreads();
        if (wv == 2 || wv == 3) {
            #pragma unroll
            for (int mt = 0; mt < 4; ++mt) {
                wtile((wv - 2) * 8 + mt, acc0[mt]);
                wtile((wv - 2) * 8 + 4 + mt, acc1[mt]);
            }
        }
        __syncthreads();
        if (wv < 2) {
            #pragma unroll
            for (int mt = 0; mt < 4; ++mt) {
                atile(wv * 8 + mt, acc0[mt]);
                atile(wv * 8 + 4 + mt, acc1[mt]);
            }
        }
        __syncthreads();
        if (wv == 1) {
            #pragma unroll
            for (int mt = 0; mt < 4; ++mt) {
                wtile(mt, acc0[mt]);
                wtile(4 + mt, acc1[mt]);
            }
        }
        __syncthreads();
        if (wv == 0) {
            #pragma unroll
            for (int mt = 0; mt < 4; ++mt) {
                atile(mt, acc0[mt]);
                atile(4 + mt, acc1[mt]);
            }
            #pragma unroll
            for (int mt = 0; mt < 4; ++mt) {
                wtile(mt, acc0[mt]);
                wtile(4 + mt, acc1[mt]);
            }
        }
        __syncthreads();

        // ---- epilogue: all 512 threads, one (b, col) each ----
        {
            int b = tid >> 3, col = tid & 7;
            int mt = b >> 4, r = b & 15;
            int base = (r >> 2) * 64 + (r & 3);   // lane-dump index of (r, c=0)
            float iv = P[mt * 256 + base + col * 4]             + bl[col];
            float fv = P[mt * 256 + base + (col + 8) * 4]       + bl[8 + col];
            float gv = P[(4 + mt) * 256 + base + col * 4]       + bl[16 + col];
            float ov = P[(4 + mt) * 256 + base + (col + 8) * 4] + bl[24 + col];
            float co = c_lds[tid];
            float ii = sigf(iv), ff = sigf(fv), gg = tanhfast(gv), oo = sigf(ov);
            float cn = ff * co + ii * gg;
            float hn = oo * tanhfast(cn);
            c_lds[tid] = cn;
            f16* dst = (layer ? p.h2all : p.h1all) + (size_t)s * (B_SZ * H_SZ);
            // write-through to coherent point (LLC): agent-scope atomic store
            unsigned short hb = __builtin_bit_cast(unsigned short, (f16)hn);
            __hip_atomic_store((unsigned short*)&dst[(size_t)b * H_SZ + jb + col], hb,
                               __ATOMIC_RELAXED, __HIP_MEMORY_SCOPE_AGENT);
        }
        __syncthreads();   // barrier drains vmcnt: all 8 waves' h stores at LLC
        if (tid == 0)
            __hip_atomic_store(myflag, s + 1, __ATOMIC_RELEASE, __HIP_MEMORY_SCOPE_AGENT);
    }
}

// ---------------------------------------------------------------------------
// Output projection: out[b,t] = h2[t,b,:] . w_out + b_out
// ---------------------------------------------------------------------------
__global__ __launch_bounds__(256) void gemv_kernel(
    const f16* __restrict__ h2all, const float* __restrict__ wout,
    const float* __restrict__ bout, float* __restrict__ out)
{
    int t = blockIdx.x;
    int wave = threadIdx.x >> 6, lane = threadIdx.x & 63;
    float w[16];
    #pragma unroll
    for (int u = 0; u < 16; ++u) w[u] = wout[lane * 16 + u];
    float b0 = bout[0];
    for (int b = wave; b < B_SZ; b += 4) {
        const f16* hp = h2all + ((size_t)t * B_SZ + b) * H_SZ + lane * 16;
        float sum = 0.f;
        #pragma unroll
        for (int u = 0; u < 16; ++u) sum += (float)hp[u] * w[u];
        #pragma unroll
        for (int off = 32; off; off >>= 1) sum += __shfl_down(sum, off, 64);
        if (lane == 0) out[(size_t)b * T_SEQ + t] = sum + b0;
    }
}

// ---------------------------------------------------------------------------
extern "C" void kernel_launch(void* const* d_in, const int* in_sizes, int n_in,
                              void* d_out, int out_size, void* d_ws, size_t ws_size,
                              hipStream_t stream)
{
    const float* x    = (const float*)d_in[0];
    const float* wih0 = (const float*)d_in[1];
    const float* whh0 = (const float*)d_in[2];
    const float* bih0 = (const float*)d_in[3];
    const float* bhh0 = (const float*)d_in[4];
    const float* wih1 = (const float*)d_in[5];
    const float* whh1 = (const float*)d_in[6];
    const float* bih1 = (const float*)d_in[7];
    const float* bhh1 = (const float*)d_in[8];
    const float* wout = (const float*)d_in[9];
    const float* bout = (const float*)d_in[10];
    float* out = (float*)d_out;

    char* ws = (char*)d_ws;
    size_t off = 0;
    auto alloc = [&](size_t bytes) -> void* {
        void* pp = ws + off;
        off += (bytes + 255) & ~(size_t)255;
        return pp;
    };
    f16* h1all = (f16*)alloc((size_t)T_SEQ * B_SZ * H_SZ * 2);    // 67 MB
    f16* h2all = (f16*)alloc((size_t)T_SEQ * B_SZ * H_SZ * 2);    // 67 MB
    int* flags = (int*)alloc(2 * 128 * FSTRIDE * 4);              // 32 KB

    (void)hipMemsetAsync(flags, 0, 2 * 128 * FSTRIDE * 4, stream);  // restart flags each replay

    Params pa;
    pa.x = x;
    pa.wih0 = wih0; pa.whh0 = whh0; pa.bih0 = bih0; pa.bhh0 = bhh0;
    pa.wih1 = wih1; pa.whh1 = whh1; pa.bih1 = bih1; pa.bhh1 = bhh1;
    pa.h1all = h1all; pa.h2all = h2all;
    pa.flags0 = flags; pa.flags1 = flags + 128 * FSTRIDE;

    (void)hipFuncSetAttribute((const void*)persist_kernel,
                              hipFuncAttributeMaxDynamicSharedMemorySize, SMEM_BYTES);

    // Cooperative launch guarantees co-residency; under graph capture fall back
    // to a plain launch (identical kernel; 146KB LDS forces 1 block/CU and
    // grid == CU count, so all 256 blocks are co-resident by construction).
    hipStreamCaptureStatus cap = hipStreamCaptureStatusNone;
    (void)hipStreamIsCapturing(stream, &cap);
    bool launched = false;
    if (cap == hipStreamCaptureStatusNone) {
        void* kargs[] = { (void*)&pa };
        if (hipLaunchCooperativeKernel((const void*)persist_kernel, dim3(NBLK), dim3(NTHR),
                                       kargs, SMEM_BYTES, stream) == hipSuccess)
            launched = true;
    }
    if (!launched)
        persist_kernel<<<NBLK, NTHR, SMEM_BYTES, stream>>>(pa);

    gemv_kernel<<<T_SEQ, 256, 0, stream>>>(h2all, wout, bout, out);
}